// Round 5
// baseline (6131.730 us; speedup 1.0000x reference)
//
#include <hip/hip_runtime.h>
#include <math.h>

#define NB   8
#define CI   64
#define COC  64
#define HQ   256
#define HK   64
#define KS   5
#define LL   256
#define NPAD 1664

// ---------------- weight transpose: [CO][CI][3][3] -> [half][CI][tap][32] ----------------
// grid (9, 64), block 64
__global__ void wtrans2_kernel(const float* __restrict__ Wt, float* __restrict__ Wo) {
  const int co = threadIdx.x;   // 0..63
  const int tap = blockIdx.x;   // 0..8
  const int ci = blockIdx.y;    // 0..63
  Wo[(((co >> 5) * 64 + ci) * 9 + tap) * 32 + (co & 31)] = Wt[(co * 64 + ci) * 9 + tap];
}

// ---------------- pad copy: src[H][W] -> dst[(H+2)][S] at +1,+1 ----------------
// grid (planes*H*W/256), block 256
__global__ void pad_copy(const float* __restrict__ src, float* __restrict__ dst,
                         int H, int W, int S, int total) {
  const int idx = blockIdx.x * 256 + threadIdx.x;
  if (idx >= total) return;
  const int p = idx / (H * W);
  const int rem = idx - p * H * W;
  const int y = rem / W, x = rem - y * W;
  dst[((size_t)p * (H + 2) + y + 1) * S + x + 1] = src[idx];
}

// ---------------- border zero: rows 0 & H+1 (full S), cols 0 & W+1 ----------------
// grid (planes), block 256
__global__ void border_zero(float* __restrict__ dst, int H, int W, int S) {
  const int p = blockIdx.x;
  float* b = dst + (size_t)p * (H + 2) * S;
  for (int c = threadIdx.x; c < S; c += 256) {
    b[c] = 0.f;
    b[(size_t)(H + 1) * S + c] = 0.f;
  }
  for (int r = 1 + threadIdx.x; r <= H; r += 256) {
    b[(size_t)r * S] = 0.f;
    b[(size_t)r * S + W + 1] = 0.f;
  }
}

// ---------------- conv 3x3 pad1 + bias + leaky relu, padded-input pipelined ----------------
// block tile: 64x X 8y X 32co. grid (W/64, H/8, NB*2). 256 threads.
// thread: xq=tid&15 (4 px), yt=(tid>>4)&3 (2 rows), cg=tid>>6 (8 co; wave-uniform)
__global__ __launch_bounds__(256, 4) void conv3p(
    const float* __restrict__ inp /*padded [(H+2)][S]*/,
    const float* __restrict__ Wts /*[half][CI][9][32]*/,
    const float* __restrict__ bias, float* __restrict__ out,
    int H, int Wd, int S) {
  const int x0 = blockIdx.x * 64;
  const int y0 = blockIdx.y * 8;
  const int z  = blockIdx.z;
  const int n  = z >> 1;
  const int half = z & 1;
  const int cob = half * 32;
  const int tid = threadIdx.x;
  const int xq = tid & 15;
  const int yt = (tid >> 4) & 3;
  const int cg = tid >> 6;
  const int Hp = H + 2;

  __shared__ float in_s[10 * 76];
  __shared__ float w_s[9 * 32];

  float acc[8][2][4];
  #pragma unroll
  for (int a = 0; a < 8; ++a)
    #pragma unroll
    for (int b = 0; b < 2; ++b)
      #pragma unroll
      for (int c = 0; c < 4; ++c) acc[a][b][c] = 0.f;

  const bool hasA = tid < 180;
  const bool hasW = (tid >= 180) && (tid < 252);
  const int arow = tid / 18, ac4 = tid - arow * 18;
  const float* gplane0 = inp + (size_t)(n * CI) * Hp * S;
  const size_t aoff = ((size_t)(y0 + arow)) * S + x0 + ac4 * 4;
  const int wi = tid - 180;
  const float* wbase = Wts + (size_t)half * 64 * 288;

  float4 sA = make_float4(0.f, 0.f, 0.f, 0.f);
  float4 sW = make_float4(0.f, 0.f, 0.f, 0.f);
  if (hasA) sA = *(const float4*)(gplane0 + aoff);
  if (hasW) sW = *(const float4*)(wbase + wi * 4);

  for (int ci = 0; ci < CI; ++ci) {
    __syncthreads();
    if (hasA) *(float4*)&in_s[arow * 76 + ac4 * 4] = sA;
    if (hasW) *(float4*)&w_s[wi * 4] = sW;
    if (ci + 1 < CI) {
      if (hasA) sA = *(const float4*)(gplane0 + (size_t)(ci + 1) * Hp * S + aoff);
      if (hasW) sW = *(const float4*)(wbase + (size_t)(ci + 1) * 288 + wi * 4);
    }
    __syncthreads();

    // my 4 rows x 6 cols
    float xin[4][6];
    const int rb = yt * 2, cb = xq * 4;
    #pragma unroll
    for (int r = 0; r < 4; ++r)
      #pragma unroll
      for (int c = 0; c < 6; ++c)
        xin[r][c] = in_s[(rb + r) * 76 + cb + c];

    #pragma unroll
    for (int tap = 0; tap < 9; ++tap) {
      const int ky = tap / 3, kx = tap % 3;
      const float4 w0 = *(const float4*)&w_s[tap * 32 + cg * 8];
      const float4 w1 = *(const float4*)&w_s[tap * 32 + cg * 8 + 4];
      const float wv[8] = {w0.x, w0.y, w0.z, w0.w, w1.x, w1.y, w1.z, w1.w};
      #pragma unroll
      for (int c8 = 0; c8 < 8; ++c8)
        #pragma unroll
        for (int dy = 0; dy < 2; ++dy)
          #pragma unroll
          for (int dx = 0; dx < 4; ++dx)
            acc[c8][dy][dx] = fmaf(wv[c8], xin[dy + ky][dx + kx], acc[c8][dy][dx]);
    }
  }

  #pragma unroll
  for (int c8 = 0; c8 < 8; ++c8) {
    const int co = cob + cg * 8 + c8;
    const float bv = bias[co];
    #pragma unroll
    for (int dy = 0; dy < 2; ++dy) {
      float4 o;
      float t;
      t = acc[c8][dy][0] + bv; o.x = t > 0.f ? t : 0.01f * t;
      t = acc[c8][dy][1] + bv; o.y = t > 0.f ? t : 0.01f * t;
      t = acc[c8][dy][2] + bv; o.z = t > 0.f ? t : 0.01f * t;
      t = acc[c8][dy][3] + bv; o.w = t > 0.f ? t : 0.01f * t;
      *(float4*)(out + ((size_t)(n * COC + co) * H + y0 + yt * 2 + dy) * Wd + x0 + xq * 4) = o;
    }
  }
}

// ---------------- k-patch squared norms ----------------
__global__ void knorm_kernel(const float* __restrict__ kfea, float* __restrict__ norms) {
  const int l = blockIdx.x, n = blockIdx.y, c = threadIdx.x;
  const int ly = l >> 4, lx = l & 15;
  const float* base = kfea + ((size_t)(n * CI + c) * HK) * HK;
  float ss = 0.f;
  #pragma unroll
  for (int i = 0; i < KS; ++i) {
    const int r = 4 * ly + i;
    if (r >= HK) continue;
    #pragma unroll
    for (int j = 0; j < KS; ++j) {
      const int cc = 4 * lx + j;
      if (cc >= HK) continue;
      const float v = base[r * HK + cc];
      ss = fmaf(v, v, ss);
    }
  }
  for (int off = 32; off; off >>= 1) ss += __shfl_down(ss, off);
  if (c == 0) norms[n * LL + l] = ss;
}

__global__ void kscale_kernel(const float* __restrict__ norms, float* __restrict__ kscale) {
  const int n = blockIdx.x, t = threadIdx.x;
  float v = norms[n * LL + t];
  for (int off = 32; off; off >>= 1) v = fmaxf(v, __shfl_down(v, off));
  __shared__ float red[4];
  if ((t & 63) == 0) red[t >> 6] = v;
  __syncthreads();
  if (t == 0) {
    const float m = fmaxf(fmaxf(red[0], red[1]), fmaxf(red[2], red[3]));
    kscale[n] = 10.0f / sqrtf(m);
  }
}

// ---------------- fused QK correlation + softmax ----------------
__global__ __launch_bounds__(256) void qk_softmax(
    const float* __restrict__ qfea, const float* __restrict__ kfea,
    const float* __restrict__ kscale, float* __restrict__ wn) {
  const int h = blockIdx.x, n = blockIdx.y;
  const int tid = threadIdx.x;
  const int lt = tid >> 4;
  const int wt = tid & 15;
  __shared__ float k_s[25 * 16 * 16];
  __shared__ float q_s[25 * 64];
  __shared__ float red[64 * 17];
  float acc[16][4];
  #pragma unroll
  for (int a = 0; a < 16; ++a)
    #pragma unroll
    for (int b = 0; b < 4; ++b) acc[a][b] = 0.f;

  const float* kb = kfea + (size_t)n * CI * HK * HK;
  const float* qb = qfea + (size_t)n * CI * HQ * HQ;

  for (int ci = 0; ci < CI; ++ci) {
    __syncthreads();
    for (int s = tid; s < 25 * 256; s += 256) {
      const int lx = s & 15, ly = (s >> 4) & 15, ij = s >> 8;
      const int i = ij / 5, j = ij % 5;
      const int r = 4 * ly + i, c = 4 * lx + j;
      k_s[s] = (r < HK && c < HK) ? kb[((size_t)ci * HK + r) * HK + c] : 0.f;
    }
    for (int s = tid; s < 25 * 64; s += 256) {
      const int w = s & 63, ij = s >> 6;
      const int i = ij / 5, j = ij % 5;
      const int gr = 4 * h + i, gc = 4 * w + j;
      q_s[s] = (gr < HQ && gc < HQ) ? qb[((size_t)ci * HQ + gr) * HQ + gc] : 0.f;
    }
    __syncthreads();
    #pragma unroll 5
    for (int ij = 0; ij < 25; ++ij) {
      const float4 q4 = *(const float4*)&q_s[ij * 64 + wt * 4];
      const float4* kp4 = (const float4*)&k_s[(ij * 16 + lt) * 16];
      const float4 k0 = kp4[0], k1 = kp4[1], k2 = kp4[2], k3 = kp4[3];
      const float kk[16] = {k0.x, k0.y, k0.z, k0.w, k1.x, k1.y, k1.z, k1.w,
                            k2.x, k2.y, k2.z, k2.w, k3.x, k3.y, k3.z, k3.w};
      const float qq[4] = {q4.x, q4.y, q4.z, q4.w};
      #pragma unroll
      for (int li = 0; li < 16; ++li)
        #pragma unroll
        for (int ww = 0; ww < 4; ++ww)
          acc[li][ww] = fmaf(kk[li], qq[ww], acc[li][ww]);
    }
  }

  const float f = kscale[n];
  #pragma unroll
  for (int li = 0; li < 16; ++li)
    #pragma unroll
    for (int ww = 0; ww < 4; ++ww) acc[li][ww] *= f;

  #pragma unroll
  for (int ww = 0; ww < 4; ++ww) {
    float m = acc[0][ww];
    #pragma unroll
    for (int li = 1; li < 16; ++li) m = fmaxf(m, acc[li][ww]);
    red[(wt * 4 + ww) * 17 + lt] = m;
  }
  __syncthreads();
  if (tid < 64) {
    float m = red[tid * 17];
    #pragma unroll
    for (int k = 1; k < 16; ++k) m = fmaxf(m, red[tid * 17 + k]);
    red[tid * 17 + 16] = m;
  }
  __syncthreads();
  float sloc[4];
  #pragma unroll
  for (int ww = 0; ww < 4; ++ww) {
    const float m = red[(wt * 4 + ww) * 17 + 16];
    float s = 0.f;
    #pragma unroll
    for (int li = 0; li < 16; ++li) {
      const float e = __expf(acc[li][ww] - m);
      acc[li][ww] = e;
      s += e;
    }
    sloc[ww] = s;
  }
  __syncthreads();
  #pragma unroll
  for (int ww = 0; ww < 4; ++ww) red[(wt * 4 + ww) * 17 + lt] = sloc[ww];
  __syncthreads();
  if (tid < 64) {
    float s = red[tid * 17];
    #pragma unroll
    for (int k = 1; k < 16; ++k) s += red[tid * 17 + k];
    red[tid * 17 + 16] = s;
  }
  __syncthreads();
  #pragma unroll
  for (int ww = 0; ww < 4; ++ww) {
    const int w = wt * 4 + ww;
    const float inv = 1.0f / red[w * 17 + 16];
    float* dst = wn + (((size_t)(n * 64 + h) * 64 + w) * 256) + lt * 16;
    #pragma unroll
    for (int q = 0; q < 4; ++q) {
      float4 o = make_float4(acc[q * 4 + 0][ww] * inv, acc[q * 4 + 1][ww] * inv,
                             acc[q * 4 + 2][ww] * inv, acc[q * 4 + 3][ww] * inv);
      *(float4*)(dst + q * 4) = o;
    }
  }
}

// ---------------- v-patch matrix gather ----------------
__global__ void vp_gather(const float* __restrict__ vfea, float* __restrict__ vp) {
  const int bij = blockIdx.x * 256 + threadIdx.x;
  const int l = blockIdx.y, n = blockIdx.z;
  if (bij >= NPAD) return;
  const int ij = bij >> 6, b = bij & 63;
  float val = 0.f;
  if (ij < 25) {
    const int i = ij / 5, j = ij % 5;
    const int ly = l >> 4, lx = l & 15;
    const int r = 4 * ly + i, c = 4 * lx + j;
    if (r < HK && c < HK) val = vfea[((size_t)(n * COC + b) * HK + r) * HK + c];
  }
  vp[((size_t)(n * LL + l)) * NPAD + bij] = val;
}

// ---------------- PV GEMM (z = batch) ----------------
__global__ __launch_bounds__(256) void pv_gemm(
    const float* __restrict__ A0, const float* __restrict__ B0, float* __restrict__ C0) {
  const int nz = blockIdx.z;
  const float* A = A0 + (size_t)nz * 4096 * 256;
  const float* Bm = B0 + (size_t)nz * LL * NPAD;
  float* C = C0 + (size_t)nz * 4096 * NPAD;
  const int m0 = blockIdx.x * 128;
  const int n0 = blockIdx.y * 128;
  const int tid = threadIdx.x;
  const int tm = tid & 15, tn = tid >> 4;
  __shared__ float As[16][132];
  __shared__ float Bs[16][128];
  float acc[8][8];
  #pragma unroll
  for (int a = 0; a < 8; ++a)
    #pragma unroll
    for (int b = 0; b < 8; ++b) acc[a][b] = 0.f;

  for (int k0 = 0; k0 < 256; k0 += 16) {
    __syncthreads();
    #pragma unroll
    for (int r = 0; r < 2; ++r) {
      const int idx = tid + r * 256;
      const int row = idx >> 2, c4 = idx & 3;
      const float4 v = *(const float4*)&A[(size_t)(m0 + row) * 256 + k0 + c4 * 4];
      As[c4 * 4 + 0][row] = v.x;
      As[c4 * 4 + 1][row] = v.y;
      As[c4 * 4 + 2][row] = v.z;
      As[c4 * 4 + 3][row] = v.w;
    }
    #pragma unroll
    for (int r = 0; r < 2; ++r) {
      const int idx = tid + r * 256;
      const int row = idx >> 5, c4 = idx & 31;
      *(float4*)&Bs[row][c4 * 4] = *(const float4*)&Bm[(size_t)(k0 + row) * NPAD + n0 + c4 * 4];
    }
    __syncthreads();
    #pragma unroll
    for (int k = 0; k < 16; ++k) {
      const float4 a0 = *(const float4*)&As[k][tm * 8];
      const float4 a1 = *(const float4*)&As[k][tm * 8 + 4];
      const float4 b0 = *(const float4*)&Bs[k][tn * 8];
      const float4 b1 = *(const float4*)&Bs[k][tn * 8 + 4];
      const float av[8] = {a0.x, a0.y, a0.z, a0.w, a1.x, a1.y, a1.z, a1.w};
      const float bv[8] = {b0.x, b0.y, b0.z, b0.w, b1.x, b1.y, b1.z, b1.w};
      #pragma unroll
      for (int mi = 0; mi < 8; ++mi)
        #pragma unroll
        for (int ni = 0; ni < 8; ++ni)
          acc[mi][ni] = fmaf(av[mi], bv[ni], acc[mi][ni]);
    }
  }
  #pragma unroll
  for (int mi = 0; mi < 8; ++mi) {
    float* dst = &C[(size_t)(m0 + tm * 8 + mi) * NPAD + n0 + tn * 8];
    *(float4*)dst = make_float4(acc[mi][0], acc[mi][1], acc[mi][2], acc[mi][3]);
    *(float4*)(dst + 4) = make_float4(acc[mi][4], acc[mi][5], acc[mi][6], acc[mi][7]);
  }
}

// ---------------- conv-transpose contribution gather (+ /6), writes padded res ----------------
// grid (4 xt, 256 y, nz); n = n0 + blockIdx.z
__global__ __launch_bounds__(256) void u_scatter(
    const float* __restrict__ U0, float* __restrict__ resp, int n0) {
  const int n = n0 + blockIdx.z;
  const float* U = U0 + (size_t)blockIdx.z * 4096 * NPAD;
  const int y = blockIdx.y;
  const int xt = blockIdx.x;
  const int tid = threadIdx.x;
  __shared__ float t_lds[64][65];
  const int ym = (y + 1) >> 2, yr = (y + 1) & 3;
  const bool v0 = (ym < 64);
  const bool v1 = (yr == 0 && ym >= 1);
  const int b = tid & 63, xg = tid >> 6;
  for (int xi = 0; xi < 16; ++xi) {
    const int x = xt * 64 + xg * 16 + xi;
    const int xm = (x + 1) >> 2, xr = (x + 1) & 3;
    const bool u0 = (xm < 64);
    const bool u1 = (xr == 0 && xm >= 1);
    float s = 0.f;
    if (v0) {
      const size_t rb = (size_t)(ym * 64) * NPAD;
      if (u0) s += U[rb + (size_t)xm * NPAD + (yr * 5 + xr) * 64 + b];
      if (u1) s += U[rb + (size_t)(xm - 1) * NPAD + (yr * 5 + 4) * 64 + b];
    }
    if (v1) {
      const size_t rb = (size_t)((ym - 1) * 64) * NPAD;
      if (u0) s += U[rb + (size_t)xm * NPAD + (4 * 5 + xr) * 64 + b];
      if (u1) s += U[rb + (size_t)(xm - 1) * NPAD + (4 * 5 + 4) * 64 + b];
    }
    t_lds[xg * 16 + xi][b] = s * (1.0f / 6.0f);
  }
  __syncthreads();
  const int xl = tid & 63, bg = tid >> 6;
  for (int bb = 0; bb < 16; ++bb) {
    const int bc = bg * 16 + bb;
    resp[((size_t)(n * COC + bc) * 258 + y + 1) * 264 + xt * 64 + xl + 1] = t_lds[xl][bc];
  }
}

extern "C" void kernel_launch(void* const* d_in, const int* in_sizes, int n_in,
                              void* d_out, int out_size, void* d_ws, size_t ws_size,
                              hipStream_t stream) {
  const float* ms   = (const float*)d_in[0];
  const float* pan  = (const float*)d_in[1];
  const float* pan2 = (const float*)d_in[2];
  const float* Wq   = (const float*)d_in[3];
  const float* bq   = (const float*)d_in[4];
  const float* Wk   = (const float*)d_in[5];
  const float* bk   = (const float*)d_in[6];
  const float* Wv   = (const float*)d_in[7];
  const float* bv   = (const float*)d_in[8];
  const float* Wr   = (const float*)d_in[9];
  const float* br   = (const float*)d_in[10];
  float* out = (float*)d_out;

  float* ws = (float*)d_ws;
  const size_t SZ_Q   = (size_t)NB * COC * HQ * HQ;          // 33.55M
  const size_t SZ_K   = (size_t)NB * CI * HK * HK;           // 2.10M
  const size_t SZ_WN  = (size_t)NB * 64 * 64 * LL;           // 8.39M
  const size_t SZ_VP  = (size_t)NB * LL * NPAD;              // 3.41M
  const size_t SZ_PB  = (size_t)NB * CI * 258 * 264;         // 34.87M (big padded)
  const size_t SZ_PS  = (size_t)NB * CI * 66 * 72;           // 2.43M (small padded)
  const size_t SZ_U1  = (size_t)4096 * NPAD;                 // 6.82M per batch
  const size_t SZ_UA  = (size_t)NB * SZ_U1;                  // 54.53M

  float* q_fea   = ws;                    // also res_pad (aliased, q/k dead by then)
  float* k_fea   = q_fea + SZ_Q;
  float* v_fea   = k_fea + SZ_K;
  float* wn      = v_fea + SZ_K;
  float* vp      = wn + SZ_WN;
  float* norms   = vp + SZ_VP;
  float* kscale  = norms + NB * LL;
  float* wtq     = kscale + 64;
  float* wtk     = wtq + 36864;
  float* wtv     = wtk + 36864;
  float* wtr     = wtv + 36864;
  float* ms_pad  = wtr + 36864;
  float* pan2pad = ms_pad + SZ_PS;
  float* shared_blk = pan2pad + SZ_PS;    // pan_pad, later U
  float* pan_pad = shared_blk;
  float* U       = shared_blk;
  float* res_pad = q_fea;                 // 34.87M over q_fea(33.55)+k_fea head

  const size_t base_elems = (size_t)(shared_blk - ws);
  const bool batched = ws_size >= (base_elems + SZ_UA) * sizeof(float);

  // weight transposes
  wtrans2_kernel<<<dim3(9, 64), 64, 0, stream>>>(Wq, wtq);
  wtrans2_kernel<<<dim3(9, 64), 64, 0, stream>>>(Wk, wtk);
  wtrans2_kernel<<<dim3(9, 64), 64, 0, stream>>>(Wv, wtv);
  wtrans2_kernel<<<dim3(9, 64), 64, 0, stream>>>(Wr, wtr);

  // pad inputs
  {
    const int totB = NB * CI * HQ * HQ;
    pad_copy<<<dim3((totB + 255) / 256), 256, 0, stream>>>(pan, pan_pad, HQ, HQ, 264, totB);
    const int totS = NB * CI * HK * HK;
    pad_copy<<<dim3((totS + 255) / 256), 256, 0, stream>>>(ms, ms_pad, HK, HK, 72, totS);
    pad_copy<<<dim3((totS + 255) / 256), 256, 0, stream>>>(pan2, pan2pad, HK, HK, 72, totS);
    border_zero<<<dim3(NB * CI), 256, 0, stream>>>(pan_pad, HQ, HQ, 264);
    border_zero<<<dim3(NB * CI), 256, 0, stream>>>(ms_pad, HK, HK, 72);
    border_zero<<<dim3(NB * CI), 256, 0, stream>>>(pan2pad, HK, HK, 72);
  }

  // feature convs
  conv3p<<<dim3(HK / 64, HK / 8, NB * 2), 256, 0, stream>>>(pan2pad, wtk, bk, k_fea, HK, HK, 72);
  conv3p<<<dim3(HK / 64, HK / 8, NB * 2), 256, 0, stream>>>(ms_pad,  wtv, bv, v_fea, HK, HK, 72);
  conv3p<<<dim3(HQ / 64, HQ / 8, NB * 2), 256, 0, stream>>>(pan_pad, wtq, bq, q_fea, HQ, HQ, 264);

  // k-patch max norm -> scale
  knorm_kernel<<<dim3(LL, NB), 64, 0, stream>>>(k_fea, norms);
  kscale_kernel<<<NB, 256, 0, stream>>>(norms, kscale);

  // attention weights (reads q_fea, k_fea -- both dead afterwards)
  qk_softmax<<<dim3(64, NB), 256, 0, stream>>>(q_fea, k_fea, kscale, wn);

  // res_pad borders (aliases q_fea/k_fea; must be after qk_softmax)
  border_zero<<<dim3(NB * CI), 256, 0, stream>>>(res_pad, HQ, HQ, 264);

  // v patch matrix
  vp_gather<<<dim3((NPAD + 255) / 256, LL, NB), 256, 0, stream>>>(v_fea, vp);

  // PV GEMM + conv-transpose gather (U aliases pan_pad; pan_pad dead after q conv)
  if (batched) {
    pv_gemm<<<dim3(32, 13, NB), 256, 0, stream>>>(wn, vp, U);
    u_scatter<<<dim3(4, HQ, NB), 256, 0, stream>>>(U, res_pad, 0);
  } else {
    for (int n = 0; n < NB; ++n) {
      pv_gemm<<<dim3(32, 13, 1), 256, 0, stream>>>(wn + (size_t)n * 4096 * 256,
                                                   vp + (size_t)n * LL * NPAD, U);
      u_scatter<<<dim3(4, HQ, 1), 256, 0, stream>>>(U, res_pad, n);
    }
  }

  // final conv (reads padded res)
  conv3p<<<dim3(HQ / 64, HQ / 8, NB * 2), 256, 0, stream>>>(res_pad, wtr, br, out, HQ, HQ, 264);
}